// Round 15
// baseline (272.518 us; speedup 1.0000x reference)
//
#include <hip/hip_runtime.h>

// ---------------- workspace layout (floats) ----------------
#define WS_FB    0          // 8*100*64   fb [b][hw][o]
#define WS_FM    51200      // 50*100*64  fm [n][ij][o]
#define WS_AM    371200     // 8*50*640 att_mem [b][n][c]
#define WS_ENC   627200     // 8*640

// ---------------- embed (blk<580) + enc (blk>=580) ----------------------------
__global__ void k_embed(const float* __restrict__ fbg, const float* __restrict__ fmg,
                        const float* __restrict__ w1x1,
                        const float* __restrict__ bns, const float* __restrict__ bnb,
                        float* __restrict__ fb, float* __restrict__ fm,
                        float* __restrict__ enc) {
  int lane = threadIdx.x;
  if (blockIdx.x >= 580) {              // encoder_output = spatial mean
    int b = blockIdx.x - 580;
    for (int c = lane; c < 640; c += 64) {
      const float4* fp = (const float4*)(fbg + (b * 640 + c) * 100);
      float s = 0.f;
#pragma unroll
      for (int t4 = 0; t4 < 25; ++t4) { float4 v = fp[t4]; s += v.x + v.y + v.z + v.w; }
      enc[b * 640 + c] = s * 0.01f;
    }
    return;
  }
  int pos0 = blockIdx.x * 10;
  const float* src; float* dst; int hw0;
  if (pos0 < 800) { int img = pos0 / 100; hw0 = pos0 % 100; src = fbg + img * 64000; dst = fb + pos0 * 64; }
  else { int p = pos0 - 800; int img = p / 100; hw0 = p % 100; src = fmg + img * 64000; dst = fm + p * 64; }

  __shared__ float xs[10][640];
  float lsum[10];
#pragma unroll
  for (int p = 0; p < 10; ++p) lsum[p] = 0.f;
  for (int i = 0; i < 10; ++i) {
    int c = lane + i * 64;
    const float* sp = src + c * 100 + hw0;
#pragma unroll
    for (int p = 0; p < 10; p += 2) {
      float2 v = *(const float2*)(sp + p);
      xs[p][c] = v.x; xs[p + 1][c] = v.y;
      lsum[p] += v.x; lsum[p + 1] += v.y;
    }
  }
  float mean[10];
#pragma unroll
  for (int p = 0; p < 10; ++p) {
    float s = lsum[p];
    for (int off = 32; off; off >>= 1) s += __shfl_down(s, off);
    mean[p] = __shfl(s, 0) * (1.f / 640.f);
  }
  __syncthreads();
  float acc[10];
#pragma unroll
  for (int p = 0; p < 10; ++p) acc[p] = 0.f;
  float wsl = 0.f;
  const float* wrow = w1x1 + lane * 640;
  for (int c4 = 0; c4 < 160; ++c4) {
    float4 w4 = *(const float4*)(wrow + c4 * 4);
    wsl += w4.x + w4.y + w4.z + w4.w;
#pragma unroll
    for (int p = 0; p < 10; ++p) {
      float4 x4 = *(const float4*)(&xs[p][c4 * 4]);
      acc[p] += w4.x * x4.x + w4.y * x4.y + w4.z * x4.z + w4.w * x4.w;
    }
  }
  float sc = bns[lane], bi = bnb[lane];
#pragma unroll
  for (int p = 0; p < 10; ++p) {
    float y = (acc[p] - mean[p] * wsl) * sc + bi;
    y = fmaxf(y, 0.f);
    float sq = y * y;
    for (int off = 32; off; off >>= 1) sq += __shfl_down(sq, off);
    float nrm = sqrtf(__shfl(sq, 0));
    dst[p * 64 + lane] = y / fmaxf(nrm, 1e-8f);
  }
}

// ====== fused corr + sep-conv4d(x2) + attn-softmax + att_mem epilogue ========
// Conv core byte-identical to R8/R12. Epilogue NEW: quad-lane coalesced feat_m
// reads (lane-quad covers 4 consecutive float4 of one c-row -> full 64B lines)
// + shfl_xor reduce, replacing the 400B-strided per-lane loads.

#define ROFF(r) (12 + (r) * 12)

#define LOAD_ROW12Z(DST, BASE, ROW, OK) {                                   \
    int _o = (OK) ? ROFF(ROW) : 0;                                          \
    float4 _a = *(const float4*)((BASE) + _o);                              \
    float4 _b = *(const float4*)((BASE) + _o + 4);                          \
    float4 _c = *(const float4*)((BASE) + _o + 8);                          \
    DST[0]=_a.x; DST[1]=_a.y; DST[2]=_a.z; DST[3]=_a.w;                     \
    DST[4]=_b.x; DST[5]=_b.y; DST[6]=_b.z; DST[7]=_b.w;                     \
    DST[8]=_c.x; DST[9]=_c.y; }

#define HW_TAPS(OUT, ROW, W0, W1, W2) {                                     \
    _Pragma("unroll") for (int w = 1; w < 10; ++w) OUT[w] += (W0)*ROW[w-1]; \
    _Pragma("unroll") for (int w = 0; w < 10; ++w) OUT[w] += (W1)*ROW[w];   \
    _Pragma("unroll") for (int w = 0; w < 9;  ++w) OUT[w] += (W2)*ROW[w+1]; }

#define UV_TAPS(ACCARR, ROW, WARR) {                                        \
    _Pragma("unroll") for (int i = 0; i < 2; ++i) {                         \
      _Pragma("unroll") for (int j = 0; j < 2; ++j) {                       \
        int du = uu - 1 - i, dv = vv - 1 - j;                               \
        if (du >= -1 && du <= 1 && dv >= -1 && dv <= 1) {                   \
          float wgt = WARR[(du+1)*3 + (dv+1)];                              \
          _Pragma("unroll") for (int w = 0; w < 10; ++w)                    \
            ACCARR[i*2+j][w] += wgt * ROW[w];                               \
        } } } }

__global__ __launch_bounds__(256, 1) void k_mid(
    const float* __restrict__ fb, const float* __restrict__ fm,
    const float* __restrict__ w1h_g, const float* __restrict__ w1u_g,
    const float* __restrict__ w2h_g, const float* __restrict__ w2u_g,
    const float* __restrict__ fmg, float* __restrict__ am)
{
  __shared__ float xs[12012];    // [0..11]=zero; corr row r at 12+12r
  __shared__ float c1[12012];    // [0..11]=zero; fb staged at [0..6800) pre-corr; later T[100][108]
  __shared__ float rcps[100];
  __shared__ float attnS[100];
  const int tid = threadIdx.x, q = blockIdx.x;
  const int b = q / 50, n = q % 50;

  const bool act = tid < 250;
  const int pu = tid / 50, prem = tid % 50, pv = prem / 10, h = prem % 10;
  const int u0 = pu * 2, v0 = pv * 2;
  const int ij0 = u0 * 10 + v0;

  if (tid < 12) xs[tid] = 0.f;           // zero row (corr never writes [0..12))

  // ---- stage fb rows into c1 (stride 68) ----
  for (int i = tid; i < 1600; i += 256) {
    int hw = i >> 4, c4 = (i & 15) << 2;
    *(float4*)(c1 + hw * 68 + c4) = *(const float4*)(fb + b * 6400 + hw * 64 + c4);
  }
  __syncthreads();

  // ---- corr: 2 passes, each computes 2 ij rows (fm pair in regs) ----
#pragma unroll 1
  for (int pass = 0; pass < 2; ++pass) {
    if (act) {
      int ijb = ij0 + pass * 10;
      float fmA[64], fmB[64];
      const float* p0 = fm + n * 6400 + ijb * 64;
#pragma unroll
      for (int c4 = 0; c4 < 16; ++c4) {
        float4 vA = *(const float4*)(p0 + c4 * 4);
        float4 vB = *(const float4*)(p0 + 64 + c4 * 4);
        fmA[c4*4+0]=vA.x; fmA[c4*4+1]=vA.y; fmA[c4*4+2]=vA.z; fmA[c4*4+3]=vA.w;
        fmB[c4*4+0]=vB.x; fmB[c4*4+1]=vB.y; fmB[c4*4+2]=vB.z; fmB[c4*4+3]=vB.w;
      }
      float a0[10], a1[10];
#pragma unroll
      for (int w = 0; w < 10; ++w) {
        const float* rw = c1 + (h * 10 + w) * 68;
        float s0 = 0.f, s1 = 0.f;
#pragma unroll
        for (int c4 = 0; c4 < 16; ++c4) {
          float4 v = *(const float4*)(rw + c4 * 4);
          s0 += v.x*fmA[4*c4] + v.y*fmA[4*c4+1] + v.z*fmA[4*c4+2] + v.w*fmA[4*c4+3];
          s1 += v.x*fmB[4*c4] + v.y*fmB[4*c4+1] + v.z*fmB[4*c4+2] + v.w*fmB[4*c4+3];
        }
        a0[w] = s0; a1[w] = s1;
      }
      float* r0p = xs + ROFF(ijb * 10 + h);
      *(float4*)(r0p)     = make_float4(a0[0],a0[1],a0[2],a0[3]);
      *(float4*)(r0p + 4) = make_float4(a0[4],a0[5],a0[6],a0[7]);
      *(float4*)(r0p + 8) = make_float4(a0[8],a0[9],0.f,0.f);
      float* r1p = xs + ROFF((ijb + 1) * 10 + h);
      *(float4*)(r1p)     = make_float4(a1[0],a1[1],a1[2],a1[3]);
      *(float4*)(r1p + 4) = make_float4(a1[4],a1[5],a1[6],a1[7]);
      *(float4*)(r1p + 8) = make_float4(a1[8],a1[9],0.f,0.f);
    }
  }
  __syncthreads();             // xs (corr) ready; c1 free

  if (tid < 12) c1[tid] = 0.f; // zero row for c1 (conv1 writes only >= 12)

  // ---- register cache: 12 PERIMETER rows of 4x4 uv neighborhood + acc ----
  float X[4][4][10];           // center 4 entries never touched -> DCE'd
  float acc[4][10];
  if (act) {
#pragma unroll
    for (int uu = 0; uu < 4; ++uu)
#pragma unroll
      for (int vv = 0; vv < 4; ++vv) {
        if (uu >= 1 && uu <= 2 && vv >= 1 && vv <= 2) continue;
        int up = u0 - 1 + uu, vp = v0 - 1 + vv;
        bool ok = (up >= 0) && (up < 10) && (vp >= 0) && (vp < 10);
        LOAD_ROW12Z(X[uu][vv], xs, (up * 10 + vp) * 10 + h, ok);
      }
#pragma unroll
    for (int oi = 0; oi < 4; ++oi)
#pragma unroll
      for (int w = 0; w < 10; ++w) acc[oi][w] = 0.f;
  }

  for (int k = 0; k < 16; ++k) {
    float wA[9], wB[9];
#pragma unroll
    for (int t = 0; t < 9; ++t) { wA[t] = w1h_g[k * 9 + t]; wB[t] = w1u_g[k * 9 + t]; }
    if (act) {
      float O4[4][10];
#pragma unroll
      for (int i = 0; i < 2; ++i)
#pragma unroll
        for (int j = 0; j < 2; ++j)
          LOAD_ROW12Z(O4[i*2+j], xs, ((u0+i)*10 + (v0+j))*10 + h, true);
#pragma unroll
      for (int i = 0; i < 2; ++i)
#pragma unroll
        for (int j = 0; j < 2; ++j) {
          int oi = i*2+j;
          float o[10];
#pragma unroll
          for (int w = 0; w < 10; ++w) o[w] = 0.f;
          HW_TAPS(o, O4[oi], wA[3], wA[4], wA[5]);
          {
            float R[10];
            LOAD_ROW12Z(R, xs, ((u0+i)*10 + (v0+j))*10 + (h-1), h > 0);
            HW_TAPS(o, R, wA[0], wA[1], wA[2]);
            LOAD_ROW12Z(R, xs, ((u0+i)*10 + (v0+j))*10 + (h+1), h < 9);
            HW_TAPS(o, R, wA[6], wA[7], wA[8]);
          }
#pragma unroll
          for (int du = -1; du <= 1; ++du)
#pragma unroll
            for (int dv = -1; dv <= 1; ++dv) {
              int ii = i + du, jj = j + dv;
              float wgt = wB[(du+1)*3 + (dv+1)];
              if (ii >= 0 && ii <= 1 && jj >= 0 && jj <= 1) {
#pragma unroll
                for (int w = 0; w < 10; ++w) o[w] += wgt * O4[ii*2+jj][w];
              } else {
#pragma unroll
                for (int w = 0; w < 10; ++w) o[w] += wgt * X[1+ii][1+jj][w];
              }
            }
          float* cp = c1 + ROFF(((u0+i)*10 + (v0+j))*10 + h);
          *(float4*)(cp)     = make_float4(fmaxf(o[0],0.f), fmaxf(o[1],0.f), fmaxf(o[2],0.f), fmaxf(o[3],0.f));
          *(float4*)(cp + 4) = make_float4(fmaxf(o[4],0.f), fmaxf(o[5],0.f), fmaxf(o[6],0.f), fmaxf(o[7],0.f));
          *(float4*)(cp + 8) = make_float4(fmaxf(o[8],0.f), fmaxf(o[9],0.f), 0.f, 0.f);
        }
    }
    __syncthreads();
#pragma unroll
    for (int t = 0; t < 9; ++t) { wA[t] = w2h_g[k * 9 + t]; wB[t] = w2u_g[k * 9 + t]; }
    if (act) {
#pragma unroll
      for (int uu = 0; uu < 4; ++uu)
#pragma unroll
        for (int vv = 0; vv < 4; ++vv) {
          float R[10];
          int up = u0 - 1 + uu, vp = v0 - 1 + vv;
          bool ok = (up >= 0) && (up < 10) && (vp >= 0) && (vp < 10);
          LOAD_ROW12Z(R, c1, (up*10 + vp)*10 + h, ok);
          UV_TAPS(acc, R, wB);
          if (uu >= 1 && uu <= 2 && vv >= 1 && vv <= 2) {
            int oi = (uu-1)*2 + (vv-1);
            HW_TAPS(acc[oi], R, wA[3], wA[4], wA[5]);
          }
        }
#pragma unroll
      for (int i = 0; i < 2; ++i)
#pragma unroll
        for (int j = 0; j < 2; ++j) {
          int oi = i*2+j;
          float R[10];
          LOAD_ROW12Z(R, c1, ((u0+i)*10 + (v0+j))*10 + (h-1), h > 0);
          HW_TAPS(acc[oi], R, wA[0], wA[1], wA[2]);
          LOAD_ROW12Z(R, c1, ((u0+i)*10 + (v0+j))*10 + (h+1), h < 9);
          HW_TAPS(acc[oi], R, wA[6], wA[7], wA[8]);
        }
    }
    __syncthreads();
  }

  // ---- attn: transpose conv output into c1 as T[hw][ij] (stride 108) ----
  if (act) {
#pragma unroll
    for (int i = 0; i < 2; ++i)
#pragma unroll
      for (int j = 0; j < 2; ++j) {
        int ij = (u0 + i) * 10 + (v0 + j);
#pragma unroll
        for (int w = 0; w < 10; ++w) c1[(h*10 + w)*108 + ij] = acc[i*2+j][w];
      }
  }
  __syncthreads();
  if (tid < 100) {
    float* row = c1 + tid * 108;
    float s = 0.f;
#pragma unroll
    for (int t4 = 0; t4 < 25; ++t4) {
      float4 v = *(const float4*)(row + t4 * 4);
      s += v.x + v.y + v.z + v.w;
    }
    float mean = s * 0.01f;
    float vs = 0.f, mx = -1e30f;
#pragma unroll
    for (int t4 = 0; t4 < 25; ++t4) {
      float4 v = *(const float4*)(row + t4 * 4);
      float d0 = v.x-mean, d1 = v.y-mean, d2 = v.z-mean, d3 = v.w-mean;
      vs += d0*d0 + d1*d1 + d2*d2 + d3*d3;
      mx = fmaxf(mx, fmaxf(fmaxf(d0, d1), fmaxf(d2, d3)));
    }
    float inv = 1.f / (5.f * sqrtf(vs * (1.f / 99.f) + 1e-5f));
    float es = 0.f;
#pragma unroll
    for (int t4 = 0; t4 < 25; ++t4) {
      float4 v = *(const float4*)(row + t4 * 4);
      float4 e;
      e.x = expf((v.x - mean - mx) * inv);
      e.y = expf((v.y - mean - mx) * inv);
      e.z = expf((v.z - mean - mx) * inv);
      e.w = expf((v.w - mean - mx) * inv);
      es += e.x + e.y + e.z + e.w;
      *(float4*)(row + t4 * 4) = e;
    }
    rcps[tid] = 1.f / es;
  }
  __syncthreads();
  if (tid < 100) {
    float s = 0.f;
    for (int hw = 0; hw < 100; ++hw) s += c1[hw * 108 + tid] * rcps[hw];
    attnS[tid] = s;
  }
  __syncthreads();

  // ---- fused att_mem, coalesced: quad q4 covers 4 consecutive float4 of one
  // c-row (full 64B line use); shfl_xor reduce within quad.
  {
    const float* fmn = fmg + n * 64000;
    const int cq = tid >> 2, q4 = tid & 3;
#pragma unroll 1
    for (int pass = 0; pass < 10; ++pass) {
      int c = pass * 64 + cq;
      const float* rowp = fmn + c * 100;
      float s = 0.f;
#pragma unroll
      for (int t4 = q4; t4 < 25; t4 += 4) {
        float4 v = *(const float4*)(rowp + t4 * 4);
        s += attnS[t4*4]*v.x + attnS[t4*4+1]*v.y + attnS[t4*4+2]*v.z + attnS[t4*4+3]*v.w;
      }
      s += __shfl_xor(s, 1);
      s += __shfl_xor(s, 2);
      if (q4 == 0) am[q * 640 + c] = s * 0.01f;
    }
  }
}

// ------- finale: cosine-sim softmax + mem_vec + FC logits, 128 blocks --------
__global__ void k_finale(const float* __restrict__ enc, const float* __restrict__ am,
                         const float* __restrict__ Wfc, const float* __restrict__ bfc,
                         float* __restrict__ out) {
  int b = blockIdx.x >> 4, jt = blockIdx.x & 15;
  int tid = threadIdx.x;
  __shared__ float cat[1280];      // [0,640)=enc, [640,1280)=mem_vec
  __shared__ float wsm[50];
  __shared__ float wred[4];
  __shared__ float part[4][64];
  for (int c = tid; c < 640; c += 256) cat[c] = enc[b * 640 + c];
  __syncthreads();
  float ps = 0.f;
  for (int c = tid; c < 640; c += 256) { float x = cat[c]; ps += x * x; }
  for (int off = 32; off; off >>= 1) ps += __shfl_down(ps, off);
  if ((tid & 63) == 0) wred[tid >> 6] = ps;
  __syncthreads();
  float en = fmaxf(sqrtf(wred[0] + wred[1] + wred[2] + wred[3]), 1e-8f);
  if (tid < 200) {
    int n2 = tid >> 2, qq = tid & 3;
    const float* ap = am + (b * 50 + n2) * 640 + qq * 160;
    const float* ep = cat + qq * 160;
    float dot = 0.f, nn = 0.f;
#pragma unroll 10
    for (int c = 0; c < 160; c += 4) {
      float4 x = *(const float4*)(ap + c);
      float4 ee = *(const float4*)(ep + c);
      dot += x.x * ee.x + x.y * ee.y + x.z * ee.z + x.w * ee.w;
      nn  += x.x * x.x + x.y * x.y + x.z * x.z + x.w * x.w;
    }
    dot += __shfl_xor(dot, 1); dot += __shfl_xor(dot, 2);
    nn  += __shfl_xor(nn, 1);  nn  += __shfl_xor(nn, 2);
    if (qq == 0) wsm[n2] = dot / (en * fmaxf(sqrtf(nn), 1e-8f));
  }
  __syncthreads();
  if (tid == 0) {
    float mx = -1e30f;
    for (int n2 = 0; n2 < 50; ++n2) mx = fmaxf(mx, wsm[n2]);
    float es = 0.f;
    for (int n2 = 0; n2 < 50; ++n2) { float ex = expf(wsm[n2] - mx); wsm[n2] = ex; es += ex; }
    float rr = 1.f / es;
    for (int n2 = 0; n2 < 50; ++n2) wsm[n2] *= rr;
  }
  __syncthreads();
  for (int c = tid; c < 640; c += 256) {
    float s = 0.f;
    for (int n2 = 0; n2 < 50; ++n2) s += wsm[n2] * am[(b * 50 + n2) * 640 + c];
    cat[640 + c] = s;
  }
  __syncthreads();
  int w = tid >> 6, jl = tid & 63;
  int j = jt * 64 + jl;
  float s0 = 0.f, s1 = 0.f, s2 = 0.f, s3 = 0.f;
  if (j < 1000) {
    const float* wp = Wfc + j;
    int c0 = w * 320;
    for (int c = c0; c < c0 + 320; c += 4) {
      s0 += cat[c]     * wp[c * 1000];
      s1 += cat[c + 1] * wp[(c + 1) * 1000];
      s2 += cat[c + 2] * wp[(c + 2) * 1000];
      s3 += cat[c + 3] * wp[(c + 3) * 1000];
    }
  }
  part[w][jl] = (s0 + s1) + (s2 + s3);
  __syncthreads();
  if (tid < 64 && j < 1000) {
    out[b * 1000 + j] = bfc[j] + ((part[0][jl] + part[1][jl]) + (part[2][jl] + part[3][jl]));
  }
}

extern "C" void kernel_launch(void* const* d_in, const int* in_sizes, int n_in,
                              void* d_out, int out_size, void* d_ws, size_t ws_size,
                              hipStream_t stream) {
  const float* feat_b = (const float*)d_in[0];
  const float* feat_m = (const float*)d_in[1];
  const float* w1x1   = (const float*)d_in[2];
  const float* bns    = (const float*)d_in[3];
  const float* bnb    = (const float*)d_in[4];
  const float* w1h    = (const float*)d_in[5];
  const float* w1u    = (const float*)d_in[6];
  const float* w2h    = (const float*)d_in[7];
  const float* w2u    = (const float*)d_in[8];
  const float* Wfc    = (const float*)d_in[9];
  const float* bfc    = (const float*)d_in[10];
  float* ws = (float*)d_ws;
  float* fbW = ws + WS_FB;  float* fmW = ws + WS_FM;
  float* am  = ws + WS_AM;  float* enc = ws + WS_ENC;

  k_embed  <<<588,  64, 0, stream>>>(feat_b, feat_m, w1x1, bns, bnb, fbW, fmW, enc);
  k_mid    <<<400, 256, 0, stream>>>(fbW, fmW, w1h, w1u, w2h, w2u, feat_m, am);
  k_finale <<<128, 256, 0, stream>>>(enc, am, Wfc, bfc, (float*)d_out);
}

// Round 16
// 266.108 us; speedup vs baseline: 1.0241x; 1.0241x over previous
//
#include <hip/hip_runtime.h>

// ---------------- workspace layout (floats) ----------------
#define WS_FB    0          // 8*100*64   fb [b][hw][o]
#define WS_FM    51200      // 50*100*64  fm [n][ij][o]
#define WS_AM    371200     // 8*50*640 att_mem [b][n][c]
#define WS_ENC   627200     // 8*640

// ---------------- embed (blk<580) + enc (blk>=580) ----------------------------
__global__ void k_embed(const float* __restrict__ fbg, const float* __restrict__ fmg,
                        const float* __restrict__ w1x1,
                        const float* __restrict__ bns, const float* __restrict__ bnb,
                        float* __restrict__ fb, float* __restrict__ fm,
                        float* __restrict__ enc) {
  int lane = threadIdx.x;
  if (blockIdx.x >= 580) {              // encoder_output = spatial mean
    int b = blockIdx.x - 580;
    for (int c = lane; c < 640; c += 64) {
      const float4* fp = (const float4*)(fbg + (b * 640 + c) * 100);
      float s = 0.f;
#pragma unroll
      for (int t4 = 0; t4 < 25; ++t4) { float4 v = fp[t4]; s += v.x + v.y + v.z + v.w; }
      enc[b * 640 + c] = s * 0.01f;
    }
    return;
  }
  int pos0 = blockIdx.x * 10;
  const float* src; float* dst; int hw0;
  if (pos0 < 800) { int img = pos0 / 100; hw0 = pos0 % 100; src = fbg + img * 64000; dst = fb + pos0 * 64; }
  else { int p = pos0 - 800; int img = p / 100; hw0 = p % 100; src = fmg + img * 64000; dst = fm + p * 64; }

  __shared__ float xs[10][640];
  float lsum[10];
#pragma unroll
  for (int p = 0; p < 10; ++p) lsum[p] = 0.f;
  for (int i = 0; i < 10; ++i) {
    int c = lane + i * 64;
    const float* sp = src + c * 100 + hw0;
#pragma unroll
    for (int p = 0; p < 10; p += 2) {
      float2 v = *(const float2*)(sp + p);
      xs[p][c] = v.x; xs[p + 1][c] = v.y;
      lsum[p] += v.x; lsum[p + 1] += v.y;
    }
  }
  float mean[10];
#pragma unroll
  for (int p = 0; p < 10; ++p) {
    float s = lsum[p];
    for (int off = 32; off; off >>= 1) s += __shfl_down(s, off);
    mean[p] = __shfl(s, 0) * (1.f / 640.f);
  }
  __syncthreads();
  float acc[10];
#pragma unroll
  for (int p = 0; p < 10; ++p) acc[p] = 0.f;
  float wsl = 0.f;
  const float* wrow = w1x1 + lane * 640;
  for (int c4 = 0; c4 < 160; ++c4) {
    float4 w4 = *(const float4*)(wrow + c4 * 4);
    wsl += w4.x + w4.y + w4.z + w4.w;
#pragma unroll
    for (int p = 0; p < 10; ++p) {
      float4 x4 = *(const float4*)(&xs[p][c4 * 4]);
      acc[p] += w4.x * x4.x + w4.y * x4.y + w4.z * x4.z + w4.w * x4.w;
    }
  }
  float sc = bns[lane], bi = bnb[lane];
#pragma unroll
  for (int p = 0; p < 10; ++p) {
    float y = (acc[p] - mean[p] * wsl) * sc + bi;
    y = fmaxf(y, 0.f);
    float sq = y * y;
    for (int off = 32; off; off >>= 1) sq += __shfl_down(sq, off);
    float nrm = sqrtf(__shfl(sq, 0));
    dst[p * 64 + lane] = y / fmaxf(nrm, 1e-8f);
  }
}

// ====== fused corr + sep-conv4d(x2) + attn-softmax + att_mem epilogue ========
// Conv core byte-identical to R8/R12's proven 188us kernel. Epilogue: attn
// stays in LDS (attnS) and am[b,n,c] is computed in-block (feat_m from L2).

#define ROFF(r) (12 + (r) * 12)

#define LOAD_ROW12Z(DST, BASE, ROW, OK) {                                   \
    int _o = (OK) ? ROFF(ROW) : 0;                                          \
    float4 _a = *(const float4*)((BASE) + _o);                              \
    float4 _b = *(const float4*)((BASE) + _o + 4);                          \
    float4 _c = *(const float4*)((BASE) + _o + 8);                          \
    DST[0]=_a.x; DST[1]=_a.y; DST[2]=_a.z; DST[3]=_a.w;                     \
    DST[4]=_b.x; DST[5]=_b.y; DST[6]=_b.z; DST[7]=_b.w;                     \
    DST[8]=_c.x; DST[9]=_c.y; }

#define HW_TAPS(OUT, ROW, W0, W1, W2) {                                     \
    _Pragma("unroll") for (int w = 1; w < 10; ++w) OUT[w] += (W0)*ROW[w-1]; \
    _Pragma("unroll") for (int w = 0; w < 10; ++w) OUT[w] += (W1)*ROW[w];   \
    _Pragma("unroll") for (int w = 0; w < 9;  ++w) OUT[w] += (W2)*ROW[w+1]; }

#define UV_TAPS(ACCARR, ROW, WARR) {                                        \
    _Pragma("unroll") for (int i = 0; i < 2; ++i) {                         \
      _Pragma("unroll") for (int j = 0; j < 2; ++j) {                       \
        int du = uu - 1 - i, dv = vv - 1 - j;                               \
        if (du >= -1 && du <= 1 && dv >= -1 && dv <= 1) {                   \
          float wgt = WARR[(du+1)*3 + (dv+1)];                              \
          _Pragma("unroll") for (int w = 0; w < 10; ++w)                    \
            ACCARR[i*2+j][w] += wgt * ROW[w];                               \
        } } } }

__global__ __launch_bounds__(256, 1) void k_mid(
    const float* __restrict__ fb, const float* __restrict__ fm,
    const float* __restrict__ w1h_g, const float* __restrict__ w1u_g,
    const float* __restrict__ w2h_g, const float* __restrict__ w2u_g,
    const float* __restrict__ fmg, float* __restrict__ am)
{
  __shared__ float xs[12012];    // [0..11]=zero; corr row r at 12+12r
  __shared__ float c1[12012];    // [0..11]=zero; fb staged at [0..6800) pre-corr; later T[100][108]
  __shared__ float rcps[100];
  __shared__ float attnS[100];
  const int tid = threadIdx.x, q = blockIdx.x;
  const int b = q / 50, n = q % 50;

  const bool act = tid < 250;
  const int pu = tid / 50, prem = tid % 50, pv = prem / 10, h = prem % 10;
  const int u0 = pu * 2, v0 = pv * 2;
  const int ij0 = u0 * 10 + v0;

  if (tid < 12) xs[tid] = 0.f;           // zero row (corr never writes [0..12))

  // ---- stage fb rows into c1 (stride 68) ----
  for (int i = tid; i < 1600; i += 256) {
    int hw = i >> 4, c4 = (i & 15) << 2;
    *(float4*)(c1 + hw * 68 + c4) = *(const float4*)(fb + b * 6400 + hw * 64 + c4);
  }
  __syncthreads();

  // ---- corr: 2 passes, each computes 2 ij rows (fm pair in regs) ----
#pragma unroll 1
  for (int pass = 0; pass < 2; ++pass) {
    if (act) {
      int ijb = ij0 + pass * 10;
      float fmA[64], fmB[64];
      const float* p0 = fm + n * 6400 + ijb * 64;
#pragma unroll
      for (int c4 = 0; c4 < 16; ++c4) {
        float4 vA = *(const float4*)(p0 + c4 * 4);
        float4 vB = *(const float4*)(p0 + 64 + c4 * 4);
        fmA[c4*4+0]=vA.x; fmA[c4*4+1]=vA.y; fmA[c4*4+2]=vA.z; fmA[c4*4+3]=vA.w;
        fmB[c4*4+0]=vB.x; fmB[c4*4+1]=vB.y; fmB[c4*4+2]=vB.z; fmB[c4*4+3]=vB.w;
      }
      float a0[10], a1[10];
#pragma unroll
      for (int w = 0; w < 10; ++w) {
        const float* rw = c1 + (h * 10 + w) * 68;
        float s0 = 0.f, s1 = 0.f;
#pragma unroll
        for (int c4 = 0; c4 < 16; ++c4) {
          float4 v = *(const float4*)(rw + c4 * 4);
          s0 += v.x*fmA[4*c4] + v.y*fmA[4*c4+1] + v.z*fmA[4*c4+2] + v.w*fmA[4*c4+3];
          s1 += v.x*fmB[4*c4] + v.y*fmB[4*c4+1] + v.z*fmB[4*c4+2] + v.w*fmB[4*c4+3];
        }
        a0[w] = s0; a1[w] = s1;
      }
      float* r0p = xs + ROFF(ijb * 10 + h);
      *(float4*)(r0p)     = make_float4(a0[0],a0[1],a0[2],a0[3]);
      *(float4*)(r0p + 4) = make_float4(a0[4],a0[5],a0[6],a0[7]);
      *(float4*)(r0p + 8) = make_float4(a0[8],a0[9],0.f,0.f);
      float* r1p = xs + ROFF((ijb + 1) * 10 + h);
      *(float4*)(r1p)     = make_float4(a1[0],a1[1],a1[2],a1[3]);
      *(float4*)(r1p + 4) = make_float4(a1[4],a1[5],a1[6],a1[7]);
      *(float4*)(r1p + 8) = make_float4(a1[8],a1[9],0.f,0.f);
    }
  }
  __syncthreads();             // xs (corr) ready; c1 free

  if (tid < 12) c1[tid] = 0.f; // zero row for c1 (conv1 writes only >= 12)

  // ---- register cache: 12 PERIMETER rows of 4x4 uv neighborhood + acc ----
  float X[4][4][10];           // center 4 entries never touched -> DCE'd
  float acc[4][10];
  if (act) {
#pragma unroll
    for (int uu = 0; uu < 4; ++uu)
#pragma unroll
      for (int vv = 0; vv < 4; ++vv) {
        if (uu >= 1 && uu <= 2 && vv >= 1 && vv <= 2) continue;
        int up = u0 - 1 + uu, vp = v0 - 1 + vv;
        bool ok = (up >= 0) && (up < 10) && (vp >= 0) && (vp < 10);
        LOAD_ROW12Z(X[uu][vv], xs, (up * 10 + vp) * 10 + h, ok);
      }
#pragma unroll
    for (int oi = 0; oi < 4; ++oi)
#pragma unroll
      for (int w = 0; w < 10; ++w) acc[oi][w] = 0.f;
  }

  for (int k = 0; k < 16; ++k) {
    float wA[9], wB[9];
#pragma unroll
    for (int t = 0; t < 9; ++t) { wA[t] = w1h_g[k * 9 + t]; wB[t] = w1u_g[k * 9 + t]; }
    if (act) {
      float O4[4][10];
#pragma unroll
      for (int i = 0; i < 2; ++i)
#pragma unroll
        for (int j = 0; j < 2; ++j)
          LOAD_ROW12Z(O4[i*2+j], xs, ((u0+i)*10 + (v0+j))*10 + h, true);
#pragma unroll
      for (int i = 0; i < 2; ++i)
#pragma unroll
        for (int j = 0; j < 2; ++j) {
          int oi = i*2+j;
          float o[10];
#pragma unroll
          for (int w = 0; w < 10; ++w) o[w] = 0.f;
          HW_TAPS(o, O4[oi], wA[3], wA[4], wA[5]);
          {
            float R[10];
            LOAD_ROW12Z(R, xs, ((u0+i)*10 + (v0+j))*10 + (h-1), h > 0);
            HW_TAPS(o, R, wA[0], wA[1], wA[2]);
            LOAD_ROW12Z(R, xs, ((u0+i)*10 + (v0+j))*10 + (h+1), h < 9);
            HW_TAPS(o, R, wA[6], wA[7], wA[8]);
          }
#pragma unroll
          for (int du = -1; du <= 1; ++du)
#pragma unroll
            for (int dv = -1; dv <= 1; ++dv) {
              int ii = i + du, jj = j + dv;
              float wgt = wB[(du+1)*3 + (dv+1)];
              if (ii >= 0 && ii <= 1 && jj >= 0 && jj <= 1) {
#pragma unroll
                for (int w = 0; w < 10; ++w) o[w] += wgt * O4[ii*2+jj][w];
              } else {
#pragma unroll
                for (int w = 0; w < 10; ++w) o[w] += wgt * X[1+ii][1+jj][w];
              }
            }
          float* cp = c1 + ROFF(((u0+i)*10 + (v0+j))*10 + h);
          *(float4*)(cp)     = make_float4(fmaxf(o[0],0.f), fmaxf(o[1],0.f), fmaxf(o[2],0.f), fmaxf(o[3],0.f));
          *(float4*)(cp + 4) = make_float4(fmaxf(o[4],0.f), fmaxf(o[5],0.f), fmaxf(o[6],0.f), fmaxf(o[7],0.f));
          *(float4*)(cp + 8) = make_float4(fmaxf(o[8],0.f), fmaxf(o[9],0.f), 0.f, 0.f);
        }
    }
    __syncthreads();
#pragma unroll
    for (int t = 0; t < 9; ++t) { wA[t] = w2h_g[k * 9 + t]; wB[t] = w2u_g[k * 9 + t]; }
    if (act) {
#pragma unroll
      for (int uu = 0; uu < 4; ++uu)
#pragma unroll
        for (int vv = 0; vv < 4; ++vv) {
          float R[10];
          int up = u0 - 1 + uu, vp = v0 - 1 + vv;
          bool ok = (up >= 0) && (up < 10) && (vp >= 0) && (vp < 10);
          LOAD_ROW12Z(R, c1, (up*10 + vp)*10 + h, ok);
          UV_TAPS(acc, R, wB);
          if (uu >= 1 && uu <= 2 && vv >= 1 && vv <= 2) {
            int oi = (uu-1)*2 + (vv-1);
            HW_TAPS(acc[oi], R, wA[3], wA[4], wA[5]);
          }
        }
#pragma unroll
      for (int i = 0; i < 2; ++i)
#pragma unroll
        for (int j = 0; j < 2; ++j) {
          int oi = i*2+j;
          float R[10];
          LOAD_ROW12Z(R, c1, ((u0+i)*10 + (v0+j))*10 + (h-1), h > 0);
          HW_TAPS(acc[oi], R, wA[0], wA[1], wA[2]);
          LOAD_ROW12Z(R, c1, ((u0+i)*10 + (v0+j))*10 + (h+1), h < 9);
          HW_TAPS(acc[oi], R, wA[6], wA[7], wA[8]);
        }
    }
    __syncthreads();
  }

  // ---- attn: transpose conv output into c1 as T[hw][ij] (stride 108) ----
  if (act) {
#pragma unroll
    for (int i = 0; i < 2; ++i)
#pragma unroll
      for (int j = 0; j < 2; ++j) {
        int ij = (u0 + i) * 10 + (v0 + j);
#pragma unroll
        for (int w = 0; w < 10; ++w) c1[(h*10 + w)*108 + ij] = acc[i*2+j][w];
      }
  }
  __syncthreads();
  if (tid < 100) {
    float* row = c1 + tid * 108;
    float s = 0.f;
#pragma unroll
    for (int t4 = 0; t4 < 25; ++t4) {
      float4 v = *(const float4*)(row + t4 * 4);
      s += v.x + v.y + v.z + v.w;
    }
    float mean = s * 0.01f;
    float vs = 0.f, mx = -1e30f;
#pragma unroll
    for (int t4 = 0; t4 < 25; ++t4) {
      float4 v = *(const float4*)(row + t4 * 4);
      float d0 = v.x-mean, d1 = v.y-mean, d2 = v.z-mean, d3 = v.w-mean;
      vs += d0*d0 + d1*d1 + d2*d2 + d3*d3;
      mx = fmaxf(mx, fmaxf(fmaxf(d0, d1), fmaxf(d2, d3)));
    }
    float inv = 1.f / (5.f * sqrtf(vs * (1.f / 99.f) + 1e-5f));
    float es = 0.f;
#pragma unroll
    for (int t4 = 0; t4 < 25; ++t4) {
      float4 v = *(const float4*)(row + t4 * 4);
      float4 e;
      e.x = expf((v.x - mean - mx) * inv);
      e.y = expf((v.y - mean - mx) * inv);
      e.z = expf((v.z - mean - mx) * inv);
      e.w = expf((v.w - mean - mx) * inv);
      es += e.x + e.y + e.z + e.w;
      *(float4*)(row + t4 * 4) = e;
    }
    rcps[tid] = 1.f / es;
  }
  __syncthreads();
  if (tid < 100) {
    float s = 0.f;
    for (int hw = 0; hw < 100; ++hw) s += c1[hw * 108 + tid] * rcps[hw];
    attnS[tid] = s;
  }
  __syncthreads();

  // ---- fused att_mem: am[b,n,c] = 0.01 * sum_ij attnS[ij] * feat_m[n,c,ij] --
  const float* fmn = fmg + n * 64000;
  for (int c = tid; c < 640; c += 256) {
    const float4* fp = (const float4*)(fmn + c * 100);
    float s = 0.f;
#pragma unroll
    for (int t4 = 0; t4 < 25; ++t4) {
      float4 v = fp[t4];
      s += attnS[t4*4]*v.x + attnS[t4*4+1]*v.y + attnS[t4*4+2]*v.z + attnS[t4*4+3]*v.w;
    }
    am[q * 640 + c] = s * 0.01f;
  }
}

// ------- finale: cosine-sim softmax + mem_vec + FC logits, 128 blocks --------
__global__ void k_finale(const float* __restrict__ enc, const float* __restrict__ am,
                         const float* __restrict__ Wfc, const float* __restrict__ bfc,
                         float* __restrict__ out) {
  int b = blockIdx.x >> 4, jt = blockIdx.x & 15;
  int tid = threadIdx.x;
  __shared__ float cat[1280];      // [0,640)=enc, [640,1280)=mem_vec
  __shared__ float wsm[50];
  __shared__ float wred[4];
  __shared__ float part[4][64];
  for (int c = tid; c < 640; c += 256) cat[c] = enc[b * 640 + c];
  __syncthreads();
  float ps = 0.f;
  for (int c = tid; c < 640; c += 256) { float x = cat[c]; ps += x * x; }
  for (int off = 32; off; off >>= 1) ps += __shfl_down(ps, off);
  if ((tid & 63) == 0) wred[tid >> 6] = ps;
  __syncthreads();
  float en = fmaxf(sqrtf(wred[0] + wred[1] + wred[2] + wred[3]), 1e-8f);
  if (tid < 200) {
    int n2 = tid >> 2, qq = tid & 3;
    const float* ap = am + (b * 50 + n2) * 640 + qq * 160;
    const float* ep = cat + qq * 160;
    float dot = 0.f, nn = 0.f;
#pragma unroll 10
    for (int c = 0; c < 160; c += 4) {
      float4 x = *(const float4*)(ap + c);
      float4 ee = *(const float4*)(ep + c);
      dot += x.x * ee.x + x.y * ee.y + x.z * ee.z + x.w * ee.w;
      nn  += x.x * x.x + x.y * x.y + x.z * x.z + x.w * x.w;
    }
    dot += __shfl_xor(dot, 1); dot += __shfl_xor(dot, 2);
    nn  += __shfl_xor(nn, 1);  nn  += __shfl_xor(nn, 2);
    if (qq == 0) wsm[n2] = dot / (en * fmaxf(sqrtf(nn), 1e-8f));
  }
  __syncthreads();
  if (tid == 0) {
    float mx = -1e30f;
    for (int n2 = 0; n2 < 50; ++n2) mx = fmaxf(mx, wsm[n2]);
    float es = 0.f;
    for (int n2 = 0; n2 < 50; ++n2) { float ex = expf(wsm[n2] - mx); wsm[n2] = ex; es += ex; }
    float rr = 1.f / es;
    for (int n2 = 0; n2 < 50; ++n2) wsm[n2] *= rr;
  }
  __syncthreads();
  for (int c = tid; c < 640; c += 256) {
    float s = 0.f;
    for (int n2 = 0; n2 < 50; ++n2) s += wsm[n2] * am[(b * 50 + n2) * 640 + c];
    cat[640 + c] = s;
  }
  __syncthreads();
  // logits: wave w sums c in [w*320, w*320+320) for its 64 j's
  int w = tid >> 6, jl = tid & 63;
  int j = jt * 64 + jl;
  float s0 = 0.f, s1 = 0.f, s2 = 0.f, s3 = 0.f;
  if (j < 1000) {
    const float* wp = Wfc + j;
    int c0 = w * 320;
    for (int c = c0; c < c0 + 320; c += 4) {
      s0 += cat[c]     * wp[c * 1000];
      s1 += cat[c + 1] * wp[(c + 1) * 1000];
      s2 += cat[c + 2] * wp[(c + 2) * 1000];
      s3 += cat[c + 3] * wp[(c + 3) * 1000];
    }
  }
  part[w][jl] = (s0 + s1) + (s2 + s3);
  __syncthreads();
  if (tid < 64 && j < 1000) {
    out[b * 1000 + j] = bfc[j] + ((part[0][jl] + part[1][jl]) + (part[2][jl] + part[3][jl]));
  }
}

extern "C" void kernel_launch(void* const* d_in, const int* in_sizes, int n_in,
                              void* d_out, int out_size, void* d_ws, size_t ws_size,
                              hipStream_t stream) {
  const float* feat_b = (const float*)d_in[0];
  const float* feat_m = (const float*)d_in[1];
  const float* w1x1   = (const float*)d_in[2];
  const float* bns    = (const float*)d_in[3];
  const float* bnb    = (const float*)d_in[4];
  const float* w1h    = (const float*)d_in[5];
  const float* w1u    = (const float*)d_in[6];
  const float* w2h    = (const float*)d_in[7];
  const float* w2u    = (const float*)d_in[8];
  const float* Wfc    = (const float*)d_in[9];
  const float* bfc    = (const float*)d_in[10];
  float* ws = (float*)d_ws;
  float* fbW = ws + WS_FB;  float* fmW = ws + WS_FM;
  float* am  = ws + WS_AM;  float* enc = ws + WS_ENC;

  k_embed  <<<588,  64, 0, stream>>>(feat_b, feat_m, w1x1, bns, bnb, fbW, fmW, enc);
  k_mid    <<<400, 256, 0, stream>>>(fbW, fmW, w1h, w1u, w2h, w2u, feat_m, am);
  k_finale <<<128, 256, 0, stream>>>(enc, am, Wfc, bfc, (float*)d_out);
}